// Round 2
// baseline (413.790 us; speedup 1.0000x reference)
//
#include <hip/hip_runtime.h>

#define NEG_SLOPE 0.2f

__device__ __forceinline__ float leaky(float v) { return v > 0.f ? v : NEG_SLOPE * v; }

// ---------------- CSR build ----------------

__global__ void k_init(int* deg, int* cursor, int N) {
    int i = blockIdx.x * blockDim.x + threadIdx.x;
    if (i < N) { deg[i] = 1; cursor[i] = 0; }  // deg starts at 1: self loop
}

__global__ void k_count(const int* dst, int E, int* deg) {
    int i = blockIdx.x * blockDim.x + threadIdx.x;
    if (i < E) atomicAdd(&deg[dst[i]], 1);
}

// single-block exclusive scan: rowptr[0]=0, rowptr[i+1]=sum deg[0..i]
__global__ void k_scan(const int* deg, int* rowptr, int N) {
    __shared__ int wsum[16];
    __shared__ int sbase;
    int tid = threadIdx.x;
    int lane = tid & 63, wid = tid >> 6;
    if (tid == 0) { sbase = 0; rowptr[0] = 0; }
    __syncthreads();
    for (int start = 0; start < N; start += 1024) {
        int i = start + tid;
        int v = (i < N) ? deg[i] : 0;
        int s = v;
        #pragma unroll
        for (int off = 1; off < 64; off <<= 1) {
            int t = __shfl_up(s, off);
            if (lane >= off) s += t;
        }
        if (lane == 63) wsum[wid] = s;
        __syncthreads();
        if (wid == 0) {
            int w = (lane < 16) ? wsum[lane] : 0;
            #pragma unroll
            for (int off = 1; off < 16; off <<= 1) {
                int t = __shfl_up(w, off);
                if (lane >= off) w += t;
            }
            if (lane < 16) wsum[lane] = w;
        }
        __syncthreads();
        int waveoff = (wid == 0) ? 0 : wsum[wid - 1];
        int incl = sbase + waveoff + s;
        if (i < N) rowptr[i + 1] = incl;
        __syncthreads();
        if (tid == 1023) sbase = incl;
        __syncthreads();
    }
}

__global__ void k_scatter(const int* src, const int* dst, int E, int N,
                          const int* rowptr, int* cursor, int* csr_src) {
    int i = blockIdx.x * blockDim.x + threadIdx.x;
    if (i < E) {
        int d = dst[i];
        int pos = rowptr[d] + atomicAdd(&cursor[d], 1);
        csr_src[pos] = src[i];
    } else if (i < E + N) {
        int n = i - E;
        int pos = rowptr[n] + atomicAdd(&cursor[n], 1);
        csr_src[pos] = n;
    }
}

// ---------------- per-layer precompute ----------------

// consts[0]=cs1, consts[1]=cd1, consts[2..66)=wsA=W2@as2, consts[66..130)=wsB=W2@ad2
__global__ void k_prep(const float* W1, const float* as1, const float* ad1,
                       const float* W2, const float* as2, const float* ad2,
                       float* consts) {
    int i = threadIdx.x;  // 64 threads
    float a = 0.f, b = 0.f;
    for (int j = 0; j < 64; j++) {
        float w = W2[i * 64 + j];
        a += w * as2[j];
        b += w * ad2[j];
    }
    consts[2 + i] = a;
    consts[66 + i] = b;
    if (i == 0) { float c = 0.f; for (int j = 0; j < 64; j++) c += W1[j] * as1[j]; consts[0] = c; }
    if (i == 1) { float c = 0.f; for (int j = 0; j < 64; j++) c += W1[j] * ad1[j]; consts[1] = c; }
}

// s2[i] = sum_j relu(agg1[i]*W1[j]+b1[j]) * wsA[j]; d2 likewise with wsB
__global__ void k_sd2(const float* agg1, const float* W1, const float* b1,
                      const float* consts, float* s2, float* d2, int N) {
    int n = (blockIdx.x * blockDim.x + threadIdx.x) >> 6;
    int lane = threadIdx.x & 63;
    if (n >= N) return;
    float t = fmaxf(fmaf(agg1[n], W1[lane], b1[lane]), 0.f);
    float a = t * consts[2 + lane];
    float b = t * consts[66 + lane];
    #pragma unroll
    for (int off = 32; off; off >>= 1) {
        a += __shfl_xor(a, off);
        b += __shfl_xor(b, off);
    }
    if (lane == 0) { s2[n] = a; d2[n] = b; }
}

// ---------------- scalar GAT layer (layers 1 and 3) ----------------
// per node n: s = val*cs, d = val*cd; e = leaky(s[src]+d[n]); online softmax;
// out[n] = (sum alpha*val[src]) (+ bias)
__global__ void k_scalar_gat(const float* val, const int* rowptr, const int* csr_src,
                             const float* cs_p, const float* cd_p,
                             const float* bias, int addb,
                             float* out, int N) {
    int n = (blockIdx.x * blockDim.x + threadIdx.x) >> 6;
    int lane = threadIdx.x & 63;
    if (n >= N) return;
    float cs = cs_p[0], cd = cd_p[0];
    float dn = val[n] * cd;
    int beg = rowptr[n], end = rowptr[n + 1];
    float m = -1e30f, den = 0.f, num = 0.f;
    for (int e = beg + lane; e < end; e += 64) {
        float v = val[csr_src[e]];
        float el = leaky(fmaf(v, cs, dn));
        float mnew = fmaxf(m, el);
        float sc = __expf(m - mnew);
        float w = __expf(el - mnew);
        den = den * sc + w;
        num = num * sc + w * v;
        m = mnew;
    }
    #pragma unroll
    for (int off = 32; off; off >>= 1) {
        float m2 = __shfl_xor(m, off);
        float dd = __shfl_xor(den, off);
        float n2 = __shfl_xor(num, off);
        float M = fmaxf(m, m2);
        float sa = __expf(m - M), sb = __expf(m2 - M);
        den = den * sa + dd * sb;
        num = num * sa + n2 * sb;
        m = M;
    }
    if (lane == 0) out[n] = num / den + (addb ? bias[0] : 0.f);
}

// ---------------- layer 2 ----------------
// pass A: online (m, den) from e=leaky(s2[src]+d2[n])
// pass B: acc[lane] = agg2[n][lane] = sum_e alpha_e * relu(agg1[src]*W1[lane]+b1[lane])
// epilogue: h2row = relu(acc @ W2 + b2); h3[n] = h2row . W3
__global__ void k_layer2(const float* agg1, const float* s2, const float* d2v,
                         const int* rowptr, const int* csr_src,
                         const float* W1, const float* b1,
                         const float* W2, const float* b2, const float* W3,
                         float* h3, int N) {
    int n = (blockIdx.x * blockDim.x + threadIdx.x) >> 6;
    int lane = threadIdx.x & 63;
    if (n >= N) return;
    int beg = rowptr[n], end = rowptr[n + 1];
    float dn = d2v[n];
    // pass A
    float m = -1e30f, den = 0.f;
    for (int e = beg + lane; e < end; e += 64) {
        float el = leaky(s2[csr_src[e]] + dn);
        float mnew = fmaxf(m, el);
        den = den * __expf(m - mnew) + __expf(el - mnew);
        m = mnew;
    }
    #pragma unroll
    for (int off = 32; off; off >>= 1) {
        float m2 = __shfl_xor(m, off), dd = __shfl_xor(den, off);
        float M = fmaxf(m, m2);
        den = den * __expf(m - M) + dd * __expf(m2 - M);
        m = M;
    }
    float inv_den = 1.f / den;
    float w1l = W1[lane], b1l = b1[lane];
    float acc = 0.f;
    // pass B: chunks of 64 edges; each lane computes one edge's (alpha, srcval),
    // then all lanes consume them via shfl for the feature-wise accumulate
    for (int cb = beg; cb < end; cb += 64) {
        int e = cb + lane;
        float alpha = 0.f, av = 0.f;
        if (e < end) {
            int sIdx = csr_src[e];
            av = agg1[sIdx];
            alpha = __expf(leaky(s2[sIdx] + dn) - m) * inv_den;
        }
        int cnt = min(64, end - cb);
        for (int k = 0; k < cnt; k++) {
            float a = __shfl(alpha, k);
            float v = __shfl(av, k);
            float t = fmaxf(fmaf(v, w1l, b1l), 0.f);
            acc = fmaf(a, t, acc);
        }
    }
    // epilogue
    float o = b2[lane];
    for (int f = 0; f < 64; f++) {
        float af = __shfl(acc, f);
        o = fmaf(af, W2[f * 64 + lane], o);
    }
    o = fmaxf(o, 0.f);
    float c = o * W3[lane];
    #pragma unroll
    for (int off = 32; off; off >>= 1) c += __shfl_xor(c, off);
    if (lane == 0) h3[n] = c;
}

// ---------------- launch ----------------

extern "C" void kernel_launch(void* const* d_in, const int* in_sizes, int n_in,
                              void* d_out, int out_size, void* d_ws, size_t ws_size,
                              hipStream_t stream) {
    const int N = in_sizes[0];          // x is [N,1]
    const int E = in_sizes[1] / 2;      // edge_index [2,E]
    const int Etot = E + N;

    const float* x   = (const float*)d_in[0];
    const int*   ei  = (const int*)d_in[1];
    const int*   src = ei;
    const int*   dst = ei + E;
    const float* W1  = (const float*)d_in[3];
    const float* as1 = (const float*)d_in[4];
    const float* ad1 = (const float*)d_in[5];
    const float* b1  = (const float*)d_in[6];
    const float* W2  = (const float*)d_in[7];
    const float* as2 = (const float*)d_in[8];
    const float* ad2 = (const float*)d_in[9];
    const float* b2  = (const float*)d_in[10];
    const float* W3  = (const float*)d_in[11];
    const float* as3 = (const float*)d_in[12];
    const float* ad3 = (const float*)d_in[13];
    const float* b3  = (const float*)d_in[14];
    float* out = (float*)d_out;

    char* p = (char*)d_ws;
    auto alloc = [&](size_t bytes) {
        char* r = p;
        p += (bytes + 255) & ~(size_t)255;
        return r;
    };
    float* consts  = (float*)alloc(130 * sizeof(float));
    int*   deg     = (int*)alloc((size_t)N * 4);
    int*   rowptr  = (int*)alloc((size_t)(N + 1) * 4);
    int*   cursor  = (int*)alloc((size_t)N * 4);
    int*   csr_src = (int*)alloc((size_t)Etot * 4);
    float* agg1    = (float*)alloc((size_t)N * 4);
    float* s2      = (float*)alloc((size_t)N * 4);
    float* d2      = (float*)alloc((size_t)N * 4);
    float* h3      = (float*)alloc((size_t)N * 4);

    const int B = 256;
    int gN   = (N + B - 1) / B;
    int gE   = (E + B - 1) / B;
    int gEt  = (Etot + B - 1) / B;
    int gW   = (N * 64 + B - 1) / B;   // wave-per-node kernels

    hipLaunchKernelGGL(k_init,    dim3(gN),  dim3(B), 0, stream, deg, cursor, N);
    hipLaunchKernelGGL(k_count,   dim3(gE),  dim3(B), 0, stream, dst, E, deg);
    hipLaunchKernelGGL(k_scan,    dim3(1),   dim3(1024), 0, stream, deg, rowptr, N);
    hipLaunchKernelGGL(k_scatter, dim3(gEt), dim3(B), 0, stream, src, dst, E, N, rowptr, cursor, csr_src);
    hipLaunchKernelGGL(k_prep,    dim3(1),   dim3(64), 0, stream, W1, as1, ad1, W2, as2, ad2, consts);

    // layer 1: agg1[n] = softmax-weighted sum of x[src]
    hipLaunchKernelGGL(k_scalar_gat, dim3(gW), dim3(B), 0, stream,
                       x, rowptr, csr_src, consts + 0, consts + 1,
                       (const float*)nullptr, 0, agg1, N);
    // layer 2 attention scalars
    hipLaunchKernelGGL(k_sd2, dim3(gW), dim3(B), 0, stream, agg1, W1, b1, consts, s2, d2, N);
    // layer 2 full: produces h3 (= h2 . W3) directly
    hipLaunchKernelGGL(k_layer2, dim3(gW), dim3(B), 0, stream,
                       agg1, s2, d2, rowptr, csr_src, W1, b1, W2, b2, W3, h3, N);
    // layer 3: scalar GAT on h3, + b3, straight to output
    hipLaunchKernelGGL(k_scalar_gat, dim3(gW), dim3(B), 0, stream,
                       h3, rowptr, csr_src, as3, ad3, b3, 1, out, N);
}